// Round 9
// baseline (637.300 us; speedup 1.0000x reference)
//
#include <hip/hip_runtime.h>

#define N_ATOMS 60000
#define FPD 120
#define HD 512
#define EE 3
#define BB 600
#define NNZ_C 5000000
#define NFORCE (3 * N_ATOMS)
#define TB 32
#define GROWS (N_ATOMS * FPD)      // 7,200,000
#define BUCK_ROWS (GROWS / 8)      // 900,000 rows per bucket -> 1.8MB bf16 slice

typedef unsigned short ushort_t;
typedef unsigned int uint_t;
typedef __attribute__((ext_vector_type(8))) __bf16 bf16x8;
typedef __attribute__((ext_vector_type(4))) float f32x4;
typedef __attribute__((ext_vector_type(4))) int i32x4;

union BF8 { f32x4 f; bf16x8 h; };

__device__ __forceinline__ ushort_t f2bf(float x) {
    uint_t u = __builtin_bit_cast(uint_t, x);
    u = (u + 0x7FFFu + ((u >> 16) & 1u)) >> 16;
    return (ushort_t)u;
}
__device__ __forceinline__ float bf2f(ushort_t s) {
    uint_t u = ((uint_t)s) << 16;
    return __builtin_bit_cast(float, u);
}
__device__ __forceinline__ float fast_tanh(float x) {
    float e2 = __expf(2.f * x);
    return fmaf(-2.f, __frcp_rn(e2 + 1.f), 1.f);
}
__device__ __forceinline__ int bucket_of(int row) { return row / BUCK_ROWS; }

// ---------------- build per-element atom lists (block-aggregated atomics) -----
__global__ __launch_bounds__(256) void build_lists(const int* __restrict__ z,
                                                   int* __restrict__ counts,
                                                   int* __restrict__ lists) {
    __shared__ int lc[3];
    __shared__ int lbase[3];
    const int t = threadIdx.x;
    if (t < 3) lc[t] = 0;
    __syncthreads();
    const int i = blockIdx.x * 256 + t;
    int e = 0, pos = 0;
    if (i < N_ATOMS) {
        int zi = z[i];
        e = (zi == 1) ? 0 : ((zi == 8) ? 1 : 2);
        pos = atomicAdd(&lc[e], 1);
    }
    __syncthreads();
    if (t < 3) lbase[t] = atomicAdd(&counts[t], lc[t]);
    __syncthreads();
    if (i < N_ATOMS) lists[e * N_ATOMS + lbase[e] + pos] = i;
}

// ---------------- pack weights into MFMA B-fragment order (bf16) ----------------
__global__ void pack_W2(const float* __restrict__ W2, ushort_t* __restrict__ W2p,
                        ushort_t* __restrict__ W2Tp) {
    int p = blockIdx.x * 256 + threadIdx.x;
    if (p >= EE * 16 * 32 * 512) return;
    int j = p & 7, L = (p >> 3) & 63, ct = (p >> 9) & 31, ks = (p >> 14) & 15, e = p >> 18;
    int k = ks * 32 + ((L >> 4) << 3) + j;
    int n = (ct << 4) + (L & 15);
    W2p[p]  = f2bf(W2[((e << 9) + k) * 512 + n]);
    W2Tp[p] = f2bf(W2[((e << 9) + n) * 512 + k]);
}
__global__ void pack_W1(const float* __restrict__ W1, ushort_t* __restrict__ W1p) {
    int p = blockIdx.x * 256 + threadIdx.x;
    if (p >= EE * 4 * 32 * 512) return;
    int j = p & 7, L = (p >> 3) & 63, ct = (p >> 9) & 31, ks = (p >> 14) & 3, e = p >> 16;
    int k = ks * 32 + ((L >> 4) << 3) + j;
    int n = (ct << 4) + (L & 15);
    W1p[p] = (k < FPD) ? f2bf(W1[(e * FPD + k) * 512 + n]) : (ushort_t)0;
}
__global__ void pack_W1T(const float* __restrict__ W1, ushort_t* __restrict__ W1Tp) {
    int p = blockIdx.x * 256 + threadIdx.x;
    if (p >= EE * 16 * 8 * 512) return;
    int j = p & 7, L = (p >> 3) & 63, ct = (p >> 9) & 7, ks = (p >> 12) & 15, e = p >> 16;
    int k = ks * 32 + ((L >> 4) << 3) + j;
    int n = (ct << 4) + (L & 15);
    W1Tp[p] = (n < FPD) ? f2bf(W1[(e * FPD + n) * 512 + k]) : (ushort_t)0;
}

#define STR 520
#define FSTR 136

// ---------------- fused fwd+bwd MLP, 32 atoms/block, 8 waves, MFMA ------------
__global__ __launch_bounds__(512, 4) void mlp_mfma(
    const float* __restrict__ fps, const int* __restrict__ image_idx,
    const float* __restrict__ b1, const float* __restrict__ b2,
    const float* __restrict__ W3, const float* __restrict__ b3,
    const ushort_t* __restrict__ W1p, const ushort_t* __restrict__ W2p,
    const ushort_t* __restrict__ W2Tp, const ushort_t* __restrict__ W1Tp,
    const int* __restrict__ counts, const int* __restrict__ lists,
    float* __restrict__ energy, ushort_t* __restrict__ g) {
    __shared__ ushort_t sH1[TB * STR];
    __shared__ ushort_t sD[TB * STR];
    __shared__ float sW3[512];
    __shared__ float eAcc[TB];
    __shared__ int sAtom[TB];
    __shared__ int sImg[TB];

    const int e = blockIdx.x % EE;
    const int tile = blockIdx.x / EE;
    const int cnt = counts[e];
    const int base = tile * TB;
    if (base >= cnt) return;
    const int nA = min(TB, cnt - base);
    const int* lst = lists + e * N_ATOMS + base;

    const int t = threadIdx.x;
    const int w = t >> 6, lane = t & 63, quad = lane >> 4, lc = lane & 15;

    if (t < TB) {
        int a = (t < nA) ? lst[t] : -1;
        sAtom[t] = a;
        sImg[t] = (a >= 0) ? image_idx[a] : 0;
        eAcc[t] = 0.f;
    }
    if (t < 512) sW3[t] = W3[e * 512 + t];
    for (int i = t; i < TB * 128; i += 512) {
        int a = i >> 7, f = i & 127;
        float v = 0.f;
        if (f < FPD && a < nA) v = __builtin_nontemporal_load(&fps[(long long)lst[a] * FPD + f]);
        sD[a * FSTR + f] = f2bf(v);
    }
    __syncthreads();

    float b1c[4], b2c[4];
#pragma unroll
    for (int c = 0; c < 4; c++) {
        int col = w * 64 + c * 16 + lc;
        b1c[c] = b1[e * 512 + col];
        b2c[c] = b2[e * 512 + col];
    }

    f32x4 acc[2][4];

    // ---- stage 1: h1 = tanh(fp @ W1 + b1) ----
#pragma unroll
    for (int rt = 0; rt < 2; rt++)
#pragma unroll
        for (int c = 0; c < 4; c++) acc[rt][c] = (f32x4)0.f;
    {
        const ushort_t* wbase = W1p + ((size_t)(e * 4) * 32 + w * 4) * 512 + lane * 8;
#pragma unroll
        for (int ks = 0; ks < 4; ks++) {
            bf16x8 a0 = *(const bf16x8*)((const char*)sD + lc * (FSTR * 2) + ks * 64 + quad * 16);
            bf16x8 a1 = *(const bf16x8*)((const char*)sD + (16 + lc) * (FSTR * 2) + ks * 64 + quad * 16);
#pragma unroll
            for (int c = 0; c < 4; c++) {
                BF8 b;
                b.f = *(const f32x4*)(wbase + ((size_t)ks * 32 + c) * 512);
                acc[0][c] = __builtin_amdgcn_mfma_f32_16x16x32_bf16(a0, b.h, acc[0][c], 0, 0, 0);
                acc[1][c] = __builtin_amdgcn_mfma_f32_16x16x32_bf16(a1, b.h, acc[1][c], 0, 0, 0);
            }
        }
    }
#pragma unroll
    for (int c = 0; c < 4; c++) {
        int col = w * 64 + c * 16 + lc;
#pragma unroll
        for (int rt = 0; rt < 2; rt++)
#pragma unroll
            for (int r = 0; r < 4; r++) {
                int row = rt * 16 + quad * 4 + r;
                sH1[row * STR + col] = f2bf(fast_tanh(acc[rt][c][r] + b1c[c]));
            }
    }
    __syncthreads();

    // ---- stage 2: h2 = tanh(h1 @ W2 + b2); dh2; energy ----
#pragma unroll
    for (int rt = 0; rt < 2; rt++)
#pragma unroll
        for (int c = 0; c < 4; c++) acc[rt][c] = (f32x4)0.f;
    {
        const ushort_t* wbase = W2p + ((size_t)(e * 16) * 32 + w * 4) * 512 + lane * 8;
#pragma unroll 2
        for (int ks = 0; ks < 16; ks++) {
            bf16x8 a0 = *(const bf16x8*)((const char*)sH1 + lc * (STR * 2) + ks * 64 + quad * 16);
            bf16x8 a1 = *(const bf16x8*)((const char*)sH1 + (16 + lc) * (STR * 2) + ks * 64 + quad * 16);
#pragma unroll
            for (int c = 0; c < 4; c++) {
                BF8 b;
                b.f = *(const f32x4*)(wbase + (size_t)ks * 32 * 512 + (size_t)c * 512);
                acc[0][c] = __builtin_amdgcn_mfma_f32_16x16x32_bf16(a0, b.h, acc[0][c], 0, 0, 0);
                acc[1][c] = __builtin_amdgcn_mfma_f32_16x16x32_bf16(a1, b.h, acc[1][c], 0, 0, 0);
            }
        }
    }
    {
        float ep[2][4];
#pragma unroll
        for (int rt = 0; rt < 2; rt++)
#pragma unroll
            for (int r = 0; r < 4; r++) ep[rt][r] = 0.f;
#pragma unroll
        for (int c = 0; c < 4; c++) {
            int col = w * 64 + c * 16 + lc;
            float w3c = sW3[col];
#pragma unroll
            for (int rt = 0; rt < 2; rt++)
#pragma unroll
                for (int r = 0; r < 4; r++) {
                    int row = rt * 16 + quad * 4 + r;
                    float h2 = fast_tanh(acc[rt][c][r] + b2c[c]);
                    ep[rt][r] += h2 * w3c;
                    sD[row * STR + col] = f2bf(w3c * (1.f - h2 * h2));
                }
        }
#pragma unroll
        for (int rt = 0; rt < 2; rt++)
#pragma unroll
            for (int r = 0; r < 4; r++) {
                float p = ep[rt][r];
                p += __shfl_xor(p, 1);
                p += __shfl_xor(p, 2);
                p += __shfl_xor(p, 4);
                p += __shfl_xor(p, 8);
                if (lc == 0) atomicAdd(&eAcc[rt * 16 + quad * 4 + r], p);
            }
    }
    __syncthreads();

    if (t < nA) atomicAdd(&energy[sImg[t]], eAcc[t] + b3[e]);

    // ---- stage 5: dh1 = (dh2 @ W2^T) * (1-h1^2) ----
#pragma unroll
    for (int rt = 0; rt < 2; rt++)
#pragma unroll
        for (int c = 0; c < 4; c++) acc[rt][c] = (f32x4)0.f;
    {
        const ushort_t* wbase = W2Tp + ((size_t)(e * 16) * 32 + w * 4) * 512 + lane * 8;
#pragma unroll 2
        for (int ks = 0; ks < 16; ks++) {
            bf16x8 a0 = *(const bf16x8*)((const char*)sD + lc * (STR * 2) + ks * 64 + quad * 16);
            bf16x8 a1 = *(const bf16x8*)((const char*)sD + (16 + lc) * (STR * 2) + ks * 64 + quad * 16);
#pragma unroll
            for (int c = 0; c < 4; c++) {
                BF8 b;
                b.f = *(const f32x4*)(wbase + (size_t)ks * 32 * 512 + (size_t)c * 512);
                acc[0][c] = __builtin_amdgcn_mfma_f32_16x16x32_bf16(a0, b.h, acc[0][c], 0, 0, 0);
                acc[1][c] = __builtin_amdgcn_mfma_f32_16x16x32_bf16(a1, b.h, acc[1][c], 0, 0, 0);
            }
        }
    }
#pragma unroll
    for (int c = 0; c < 4; c++) {
        int col = w * 64 + c * 16 + lc;
#pragma unroll
        for (int rt = 0; rt < 2; rt++)
#pragma unroll
            for (int r = 0; r < 4; r++) {
                int row = rt * 16 + quad * 4 + r;
                float h1v = bf2f(sH1[row * STR + col]);
                acc[rt][c][r] *= (1.f - h1v * h1v);
            }
    }
    __syncthreads();
#pragma unroll
    for (int c = 0; c < 4; c++) {
        int col = w * 64 + c * 16 + lc;
#pragma unroll
        for (int rt = 0; rt < 2; rt++)
#pragma unroll
            for (int r = 0; r < 4; r++) {
                int row = rt * 16 + quad * 4 + r;
                sH1[row * STR + col] = f2bf(acc[rt][c][r]);
            }
    }
    __syncthreads();

    // ---- stage 7: g = dh1 @ W1^T ----
    f32x4 acc7[2];
#pragma unroll
    for (int rt = 0; rt < 2; rt++) acc7[rt] = (f32x4)0.f;
    {
        const ushort_t* wbase = W1Tp + ((size_t)(e * 16) * 8 + w) * 512 + lane * 8;
#pragma unroll 2
        for (int ks = 0; ks < 16; ks++) {
            bf16x8 a0 = *(const bf16x8*)((const char*)sH1 + lc * (STR * 2) + ks * 64 + quad * 16);
            bf16x8 a1 = *(const bf16x8*)((const char*)sH1 + (16 + lc) * (STR * 2) + ks * 64 + quad * 16);
            BF8 b;
            b.f = *(const f32x4*)(wbase + (size_t)ks * 8 * 512);
            acc7[0] = __builtin_amdgcn_mfma_f32_16x16x32_bf16(a0, b.h, acc7[0], 0, 0, 0);
            acc7[1] = __builtin_amdgcn_mfma_f32_16x16x32_bf16(a1, b.h, acc7[1], 0, 0, 0);
        }
    }
    {
        int col = w * 16 + lc;
#pragma unroll
        for (int rt = 0; rt < 2; rt++)
#pragma unroll
            for (int r = 0; r < 4; r++) {
                int row = rt * 16 + quad * 4 + r;
                if (col < FPD && row < nA)
                    g[(long long)sAtom[row] * FPD + col] = f2bf(acc7[rt][r]);
            }
    }
}

// ---------------- bucketing: shard nnz by g-row range (XCD L2 locality) -------
// pass 1: global 8-bin histogram (block-aggregated)
__global__ __launch_bounds__(256) void bucket_hist(const int* __restrict__ rows,
                                                   int* __restrict__ bcnt) {
    __shared__ int h[8];
    const int t = threadIdx.x;
    if (t < 8) h[t] = 0;
    __syncthreads();
    const int nv = NNZ_C / 4;
    for (int vk = blockIdx.x * 256 + t; vk < nv; vk += gridDim.x * 256) {
        i32x4 r = __builtin_nontemporal_load((const i32x4*)rows + vk);
        atomicAdd(&h[bucket_of(r.x)], 1);
        atomicAdd(&h[bucket_of(r.y)], 1);
        atomicAdd(&h[bucket_of(r.z)], 1);
        atomicAdd(&h[bucket_of(r.w)], 1);
    }
    __syncthreads();
    if (t < 8) atomicAdd(&bcnt[t], h[t]);
}

// pass 2: exclusive scan (8 values)
__global__ void bucket_scan(const int* __restrict__ bcnt, int* __restrict__ bbase,
                            int* __restrict__ bcur) {
    if (threadIdx.x == 0 && blockIdx.x == 0) {
        int s = 0;
        for (int i = 0; i < 8; i++) { bbase[i] = s; bcur[i] = s; s += bcnt[i]; }
    }
}

// pass 3: scatter nnz into buckets. 8192 entries/block, LDS-aggregated
// reservation -> only 8 global atomics per block (611 blocks).
__global__ __launch_bounds__(256) void bucket_scatter(
    const int* __restrict__ rows, const int* __restrict__ cols,
    const float* __restrict__ vals, int* __restrict__ bcur,
    int* __restrict__ brows, int* __restrict__ bcols, float* __restrict__ bvals) {
    __shared__ int lcnt[8];
    __shared__ int lcur[8];
    const int t = threadIdx.x;
    if (t < 8) lcnt[t] = 0;
    __syncthreads();
    const int vk0 = blockIdx.x * 2048;  // 2048 vec4 = 8192 entries
    i32x4 rcache[8];
    int nb[8][4];
#pragma unroll
    for (int i = 0; i < 8; i++) {
        int vk = vk0 + i * 256 + t;
        if (vk * 4 < NNZ_C) {
            i32x4 r = __builtin_nontemporal_load((const i32x4*)rows + vk);
            rcache[i] = r;
            nb[i][0] = bucket_of(r.x); nb[i][1] = bucket_of(r.y);
            nb[i][2] = bucket_of(r.z); nb[i][3] = bucket_of(r.w);
            atomicAdd(&lcnt[nb[i][0]], 1);
            atomicAdd(&lcnt[nb[i][1]], 1);
            atomicAdd(&lcnt[nb[i][2]], 1);
            atomicAdd(&lcnt[nb[i][3]], 1);
        } else {
            nb[i][0] = -1;
        }
    }
    __syncthreads();
    if (t < 8) lcur[t] = atomicAdd(&bcur[t], lcnt[t]);
    __syncthreads();
#pragma unroll
    for (int i = 0; i < 8; i++) {
        int vk = vk0 + i * 256 + t;
        if (vk * 4 < NNZ_C) {
            i32x4 c = __builtin_nontemporal_load((const i32x4*)cols + vk);
            f32x4 v = __builtin_nontemporal_load((const f32x4*)vals + vk);
            int rr[4] = {rcache[i].x, rcache[i].y, rcache[i].z, rcache[i].w};
            int cc[4] = {c.x, c.y, c.z, c.w};
            float vv[4] = {v.x, v.y, v.z, v.w};
#pragma unroll
            for (int u = 0; u < 4; u++) {
                int pos = atomicAdd(&lcur[nb[i][u]], 1);
                brows[pos] = rr[u];
                bcols[pos] = cc[u];
                bvals[pos] = vv[u];
            }
        }
    }
}

// pass 4: force scatter; block b handles bucket b&7 (its XCD under round-robin
// dispatch) -> g slice (1.8MB) + forcesP slot (720KB) are L2-resident.
__global__ __launch_bounds__(256) void scatter_bucketed(
    const int* __restrict__ brows, const int* __restrict__ bcols,
    const float* __restrict__ bvals, const int* __restrict__ bbase,
    const int* __restrict__ bcnt, const ushort_t* __restrict__ g,
    float* __restrict__ forcesP) {
    const int s = blockIdx.x & 7;
    const int lb = blockIdx.x >> 3;
    const int nlb = gridDim.x >> 3;
    const int base = bbase[s];
    const int end = base + bcnt[s];
    float* fp = forcesP + (size_t)s * NFORCE;
    for (int i = base + lb * 256 + threadIdx.x; i < end; i += nlb * 256) {
        int r = brows[i];
        int c = bcols[i];
        float v = bvals[i];
        atomicAdd(&fp[c], -v * bf2f(g[r]));
    }
}

// fallback direct scatter (used when ws too small for buckets)
__global__ __launch_bounds__(256) void scatter_forces(
    const int* __restrict__ rows, const int* __restrict__ cols,
    const float* __restrict__ vals, const ushort_t* __restrict__ g,
    float* __restrict__ forcesP) {
    int k = blockIdx.x * 256 + threadIdx.x;
    if (k >= NNZ_C / 4) return;
    int slot = blockIdx.x & 7;
    i32x4 r = __builtin_nontemporal_load((const i32x4*)rows + k);
    i32x4 c = __builtin_nontemporal_load((const i32x4*)cols + k);
    f32x4 v = __builtin_nontemporal_load((const f32x4*)vals + k);
    float* fp = forcesP + (size_t)slot * NFORCE;
    atomicAdd(&fp[c.x], -v.x * bf2f(g[r.x]));
    atomicAdd(&fp[c.y], -v.y * bf2f(g[r.y]));
    atomicAdd(&fp[c.z], -v.z * bf2f(g[r.z]));
    atomicAdd(&fp[c.w], -v.w * bf2f(g[r.w]));
}

__global__ void reduce_forces(const float* __restrict__ forcesP, float* __restrict__ forces) {
    int i = blockIdx.x * blockDim.x + threadIdx.x;
    if (i >= NFORCE) return;
    float s = 0.f;
#pragma unroll
    for (int x = 0; x < 8; x++) s += forcesP[x * NFORCE + i];
    forces[i] = s;
}

extern "C" void kernel_launch(void* const* d_in, const int* in_sizes, int n_in,
                              void* d_out, int out_size, void* d_ws, size_t ws_size,
                              hipStream_t stream) {
    const float* fps = (const float*)d_in[0];
    const int* z = (const int*)d_in[1];
    const int* img = (const int*)d_in[2];
    const float* W1 = (const float*)d_in[3];
    const float* b1 = (const float*)d_in[4];
    const float* W2 = (const float*)d_in[5];
    const float* b2 = (const float*)d_in[6];
    const float* W3 = (const float*)d_in[7];
    const float* b3 = (const float*)d_in[8];
    const int* rows = (const int*)d_in[9];
    const int* cols = (const int*)d_in[10];
    const float* vals = (const float*)d_in[11];

    float* out = (float*)d_out;
    float* energy = out;
    float* forces = out + BB;

    char* ws = (char*)d_ws;
    int* counts = (int*)ws;                           // 256 B
    int* lists = (int*)(ws + 256);                    // 720000 B
    ushort_t* W1p = (ushort_t*)(ws + 720384);         // 393216 B
    ushort_t* W2p = (ushort_t*)(ws + 1113600);        // 1572864 B
    ushort_t* W2Tp = (ushort_t*)(ws + 2686464);       // 1572864 B
    ushort_t* W1Tp = (ushort_t*)(ws + 4259328);       // 393216 B
    ushort_t* g = (ushort_t*)(ws + 4652544);          // 14400000 B
    float* forcesP = (float*)(ws + 19052544);         // 5760000 B
    int* bmeta = (int*)(ws + 24812544);               // 96 B: bcnt[8],bbase[8],bcur[8]
    int* bcnt = bmeta, *bbase = bmeta + 8, *bcur = bmeta + 16;
    int* brows = (int*)(ws + 24812800);               // 20 MB
    int* bcols = (int*)(ws + 44812800);               // 20 MB
    float* bvals = (float*)(ws + 64812800);           // 20 MB -> 84812800 total
    const size_t WS_NEED = 84812800;
    (void)in_sizes; (void)n_in; (void)out_size;

    (void)hipMemsetAsync(d_out, 0, (size_t)(BB + NFORCE) * sizeof(float), stream);
    (void)hipMemsetAsync(counts, 0, 256, stream);
    (void)hipMemsetAsync(forcesP, 0, (size_t)8 * NFORCE * sizeof(float), stream);

    build_lists<<<(N_ATOMS + 255) / 256, 256, 0, stream>>>(z, counts, lists);
    pack_W2<<<(EE * 16 * 32 * 512 + 255) / 256, 256, 0, stream>>>(W2, W2p, W2Tp);
    pack_W1<<<(EE * 4 * 32 * 512 + 255) / 256, 256, 0, stream>>>(W1, W1p);
    pack_W1T<<<(EE * 16 * 8 * 512 + 255) / 256, 256, 0, stream>>>(W1, W1Tp);

    int tiles = (N_ATOMS + TB - 1) / TB;
    mlp_mfma<<<EE * tiles, 512, 0, stream>>>(fps, img, b1, b2, W3, b3,
                                             W1p, W2p, W2Tp, W1Tp,
                                             counts, lists, energy, g);

    if (ws_size >= WS_NEED) {
        (void)hipMemsetAsync(bmeta, 0, 96, stream);
        bucket_hist<<<256, 256, 0, stream>>>(rows, bcnt);
        bucket_scan<<<1, 64, 0, stream>>>(bcnt, bbase, bcur);
        bucket_scatter<<<(NNZ_C + 8191) / 8192, 256, 0, stream>>>(
            rows, cols, vals, bcur, brows, bcols, bvals);
        scatter_bucketed<<<2048, 256, 0, stream>>>(brows, bcols, bvals, bbase,
                                                   bcnt, g, forcesP);
    } else {
        scatter_forces<<<(NNZ_C / 4 + 255) / 256, 256, 0, stream>>>(rows, cols, vals, g, forcesP);
    }
    reduce_forces<<<(NFORCE + 255) / 256, 256, 0, stream>>>(forcesP, forces);
}

// Round 10
// 494.526 us; speedup vs baseline: 1.2887x; 1.2887x over previous
//
#include <hip/hip_runtime.h>

#define N_ATOMS 60000
#define FPD 120
#define HD 512
#define EE 3
#define BB 600
#define NNZ_C 5000000
#define NFORCE (3 * N_ATOMS)
#define TB 32
#define CBITS 12                       // 4096 cols per bucket (16KB f32 LDS)
#define NBUCK ((NFORCE + 4095) / 4096) // 44

typedef unsigned short ushort_t;
typedef unsigned int uint_t;
typedef __attribute__((ext_vector_type(8))) __bf16 bf16x8;
typedef __attribute__((ext_vector_type(4))) float f32x4;
typedef __attribute__((ext_vector_type(4))) int i32x4;

union BF8 { f32x4 f; bf16x8 h; };

__device__ __forceinline__ ushort_t f2bf(float x) {
    uint_t u = __builtin_bit_cast(uint_t, x);
    u = (u + 0x7FFFu + ((u >> 16) & 1u)) >> 16;
    return (ushort_t)u;
}
__device__ __forceinline__ float bf2f(ushort_t s) {
    uint_t u = ((uint_t)s) << 16;
    return __builtin_bit_cast(float, u);
}
__device__ __forceinline__ float fast_tanh(float x) {
    float e2 = __expf(2.f * x);
    return fmaf(-2.f, __frcp_rn(e2 + 1.f), 1.f);
}

// ---------------- build per-element atom lists (block-aggregated atomics) -----
__global__ __launch_bounds__(256) void build_lists(const int* __restrict__ z,
                                                   int* __restrict__ counts,
                                                   int* __restrict__ lists) {
    __shared__ int lc[3];
    __shared__ int lbase[3];
    const int t = threadIdx.x;
    if (t < 3) lc[t] = 0;
    __syncthreads();
    const int i = blockIdx.x * 256 + t;
    int e = 0, pos = 0;
    if (i < N_ATOMS) {
        int zi = z[i];
        e = (zi == 1) ? 0 : ((zi == 8) ? 1 : 2);
        pos = atomicAdd(&lc[e], 1);
    }
    __syncthreads();
    if (t < 3) lbase[t] = atomicAdd(&counts[t], lc[t]);
    __syncthreads();
    if (i < N_ATOMS) lists[e * N_ATOMS + lbase[e] + pos] = i;
}

// ---------------- pack weights into MFMA B-fragment order (bf16) ----------------
__global__ void pack_W2(const float* __restrict__ W2, ushort_t* __restrict__ W2p,
                        ushort_t* __restrict__ W2Tp) {
    int p = blockIdx.x * 256 + threadIdx.x;
    if (p >= EE * 16 * 32 * 512) return;
    int j = p & 7, L = (p >> 3) & 63, ct = (p >> 9) & 31, ks = (p >> 14) & 15, e = p >> 18;
    int k = ks * 32 + ((L >> 4) << 3) + j;
    int n = (ct << 4) + (L & 15);
    W2p[p]  = f2bf(W2[((e << 9) + k) * 512 + n]);
    W2Tp[p] = f2bf(W2[((e << 9) + n) * 512 + k]);
}
__global__ void pack_W1(const float* __restrict__ W1, ushort_t* __restrict__ W1p) {
    int p = blockIdx.x * 256 + threadIdx.x;
    if (p >= EE * 4 * 32 * 512) return;
    int j = p & 7, L = (p >> 3) & 63, ct = (p >> 9) & 31, ks = (p >> 14) & 3, e = p >> 16;
    int k = ks * 32 + ((L >> 4) << 3) + j;
    int n = (ct << 4) + (L & 15);
    W1p[p] = (k < FPD) ? f2bf(W1[(e * FPD + k) * 512 + n]) : (ushort_t)0;
}
__global__ void pack_W1T(const float* __restrict__ W1, ushort_t* __restrict__ W1Tp) {
    int p = blockIdx.x * 256 + threadIdx.x;
    if (p >= EE * 16 * 8 * 512) return;
    int j = p & 7, L = (p >> 3) & 63, ct = (p >> 9) & 7, ks = (p >> 12) & 15, e = p >> 16;
    int k = ks * 32 + ((L >> 4) << 3) + j;
    int n = (ct << 4) + (L & 15);
    W1Tp[p] = (n < FPD) ? f2bf(W1[(e * FPD + n) * 512 + k]) : (ushort_t)0;
}

#define STR 520
#define FSTR 136

// ---------------- fused fwd+bwd MLP, 32 atoms/block, 8 waves, MFMA ------------
__global__ __launch_bounds__(512, 4) void mlp_mfma(
    const float* __restrict__ fps, const int* __restrict__ image_idx,
    const float* __restrict__ b1, const float* __restrict__ b2,
    const float* __restrict__ W3, const float* __restrict__ b3,
    const ushort_t* __restrict__ W1p, const ushort_t* __restrict__ W2p,
    const ushort_t* __restrict__ W2Tp, const ushort_t* __restrict__ W1Tp,
    const int* __restrict__ counts, const int* __restrict__ lists,
    float* __restrict__ energy, ushort_t* __restrict__ g) {
    __shared__ ushort_t sH1[TB * STR];
    __shared__ ushort_t sD[TB * STR];
    __shared__ float sW3[512];
    __shared__ float eAcc[TB];
    __shared__ int sAtom[TB];
    __shared__ int sImg[TB];

    const int e = blockIdx.x % EE;
    const int tile = blockIdx.x / EE;
    const int cnt = counts[e];
    const int base = tile * TB;
    if (base >= cnt) return;
    const int nA = min(TB, cnt - base);
    const int* lst = lists + e * N_ATOMS + base;

    const int t = threadIdx.x;
    const int w = t >> 6, lane = t & 63, quad = lane >> 4, lc = lane & 15;

    if (t < TB) {
        int a = (t < nA) ? lst[t] : -1;
        sAtom[t] = a;
        sImg[t] = (a >= 0) ? image_idx[a] : 0;
        eAcc[t] = 0.f;
    }
    if (t < 512) sW3[t] = W3[e * 512 + t];
    for (int i = t; i < TB * 128; i += 512) {
        int a = i >> 7, f = i & 127;
        float v = 0.f;
        if (f < FPD && a < nA) v = __builtin_nontemporal_load(&fps[(long long)lst[a] * FPD + f]);
        sD[a * FSTR + f] = f2bf(v);
    }
    __syncthreads();

    float b1c[4], b2c[4];
#pragma unroll
    for (int c = 0; c < 4; c++) {
        int col = w * 64 + c * 16 + lc;
        b1c[c] = b1[e * 512 + col];
        b2c[c] = b2[e * 512 + col];
    }

    f32x4 acc[2][4];

    // ---- stage 1: h1 = tanh(fp @ W1 + b1) ----
#pragma unroll
    for (int rt = 0; rt < 2; rt++)
#pragma unroll
        for (int c = 0; c < 4; c++) acc[rt][c] = (f32x4)0.f;
    {
        const ushort_t* wbase = W1p + ((size_t)(e * 4) * 32 + w * 4) * 512 + lane * 8;
#pragma unroll
        for (int ks = 0; ks < 4; ks++) {
            bf16x8 a0 = *(const bf16x8*)((const char*)sD + lc * (FSTR * 2) + ks * 64 + quad * 16);
            bf16x8 a1 = *(const bf16x8*)((const char*)sD + (16 + lc) * (FSTR * 2) + ks * 64 + quad * 16);
#pragma unroll
            for (int c = 0; c < 4; c++) {
                BF8 b;
                b.f = *(const f32x4*)(wbase + ((size_t)ks * 32 + c) * 512);
                acc[0][c] = __builtin_amdgcn_mfma_f32_16x16x32_bf16(a0, b.h, acc[0][c], 0, 0, 0);
                acc[1][c] = __builtin_amdgcn_mfma_f32_16x16x32_bf16(a1, b.h, acc[1][c], 0, 0, 0);
            }
        }
    }
#pragma unroll
    for (int c = 0; c < 4; c++) {
        int col = w * 64 + c * 16 + lc;
#pragma unroll
        for (int rt = 0; rt < 2; rt++)
#pragma unroll
            for (int r = 0; r < 4; r++) {
                int row = rt * 16 + quad * 4 + r;
                sH1[row * STR + col] = f2bf(fast_tanh(acc[rt][c][r] + b1c[c]));
            }
    }
    __syncthreads();

    // ---- stage 2: h2 = tanh(h1 @ W2 + b2); dh2; energy ----
#pragma unroll
    for (int rt = 0; rt < 2; rt++)
#pragma unroll
        for (int c = 0; c < 4; c++) acc[rt][c] = (f32x4)0.f;
    {
        const ushort_t* wbase = W2p + ((size_t)(e * 16) * 32 + w * 4) * 512 + lane * 8;
#pragma unroll 2
        for (int ks = 0; ks < 16; ks++) {
            bf16x8 a0 = *(const bf16x8*)((const char*)sH1 + lc * (STR * 2) + ks * 64 + quad * 16);
            bf16x8 a1 = *(const bf16x8*)((const char*)sH1 + (16 + lc) * (STR * 2) + ks * 64 + quad * 16);
#pragma unroll
            for (int c = 0; c < 4; c++) {
                BF8 b;
                b.f = *(const f32x4*)(wbase + (size_t)ks * 32 * 512 + (size_t)c * 512);
                acc[0][c] = __builtin_amdgcn_mfma_f32_16x16x32_bf16(a0, b.h, acc[0][c], 0, 0, 0);
                acc[1][c] = __builtin_amdgcn_mfma_f32_16x16x32_bf16(a1, b.h, acc[1][c], 0, 0, 0);
            }
        }
    }
    {
        float ep[2][4];
#pragma unroll
        for (int rt = 0; rt < 2; rt++)
#pragma unroll
            for (int r = 0; r < 4; r++) ep[rt][r] = 0.f;
#pragma unroll
        for (int c = 0; c < 4; c++) {
            int col = w * 64 + c * 16 + lc;
            float w3c = sW3[col];
#pragma unroll
            for (int rt = 0; rt < 2; rt++)
#pragma unroll
                for (int r = 0; r < 4; r++) {
                    int row = rt * 16 + quad * 4 + r;
                    float h2 = fast_tanh(acc[rt][c][r] + b2c[c]);
                    ep[rt][r] += h2 * w3c;
                    sD[row * STR + col] = f2bf(w3c * (1.f - h2 * h2));
                }
        }
#pragma unroll
        for (int rt = 0; rt < 2; rt++)
#pragma unroll
            for (int r = 0; r < 4; r++) {
                float p = ep[rt][r];
                p += __shfl_xor(p, 1);
                p += __shfl_xor(p, 2);
                p += __shfl_xor(p, 4);
                p += __shfl_xor(p, 8);
                if (lc == 0) atomicAdd(&eAcc[rt * 16 + quad * 4 + r], p);
            }
    }
    __syncthreads();

    if (t < nA) atomicAdd(&energy[sImg[t]], eAcc[t] + b3[e]);

    // ---- stage 5: dh1 = (dh2 @ W2^T) * (1-h1^2) ----
#pragma unroll
    for (int rt = 0; rt < 2; rt++)
#pragma unroll
        for (int c = 0; c < 4; c++) acc[rt][c] = (f32x4)0.f;
    {
        const ushort_t* wbase = W2Tp + ((size_t)(e * 16) * 32 + w * 4) * 512 + lane * 8;
#pragma unroll 2
        for (int ks = 0; ks < 16; ks++) {
            bf16x8 a0 = *(const bf16x8*)((const char*)sD + lc * (STR * 2) + ks * 64 + quad * 16);
            bf16x8 a1 = *(const bf16x8*)((const char*)sD + (16 + lc) * (STR * 2) + ks * 64 + quad * 16);
#pragma unroll
            for (int c = 0; c < 4; c++) {
                BF8 b;
                b.f = *(const f32x4*)(wbase + (size_t)ks * 32 * 512 + (size_t)c * 512);
                acc[0][c] = __builtin_amdgcn_mfma_f32_16x16x32_bf16(a0, b.h, acc[0][c], 0, 0, 0);
                acc[1][c] = __builtin_amdgcn_mfma_f32_16x16x32_bf16(a1, b.h, acc[1][c], 0, 0, 0);
            }
        }
    }
#pragma unroll
    for (int c = 0; c < 4; c++) {
        int col = w * 64 + c * 16 + lc;
#pragma unroll
        for (int rt = 0; rt < 2; rt++)
#pragma unroll
            for (int r = 0; r < 4; r++) {
                int row = rt * 16 + quad * 4 + r;
                float h1v = bf2f(sH1[row * STR + col]);
                acc[rt][c][r] *= (1.f - h1v * h1v);
            }
    }
    __syncthreads();
#pragma unroll
    for (int c = 0; c < 4; c++) {
        int col = w * 64 + c * 16 + lc;
#pragma unroll
        for (int rt = 0; rt < 2; rt++)
#pragma unroll
            for (int r = 0; r < 4; r++) {
                int row = rt * 16 + quad * 4 + r;
                sH1[row * STR + col] = f2bf(acc[rt][c][r]);
            }
    }
    __syncthreads();

    // ---- stage 7: g = dh1 @ W1^T ----
    f32x4 acc7[2];
#pragma unroll
    for (int rt = 0; rt < 2; rt++) acc7[rt] = (f32x4)0.f;
    {
        const ushort_t* wbase = W1Tp + ((size_t)(e * 16) * 8 + w) * 512 + lane * 8;
#pragma unroll 2
        for (int ks = 0; ks < 16; ks++) {
            bf16x8 a0 = *(const bf16x8*)((const char*)sH1 + lc * (STR * 2) + ks * 64 + quad * 16);
            bf16x8 a1 = *(const bf16x8*)((const char*)sH1 + (16 + lc) * (STR * 2) + ks * 64 + quad * 16);
            BF8 b;
            b.f = *(const f32x4*)(wbase + (size_t)ks * 8 * 512);
            acc7[0] = __builtin_amdgcn_mfma_f32_16x16x32_bf16(a0, b.h, acc7[0], 0, 0, 0);
            acc7[1] = __builtin_amdgcn_mfma_f32_16x16x32_bf16(a1, b.h, acc7[1], 0, 0, 0);
        }
    }
    {
        int col = w * 16 + lc;
#pragma unroll
        for (int rt = 0; rt < 2; rt++)
#pragma unroll
            for (int r = 0; r < 4; r++) {
                int row = rt * 16 + quad * 4 + r;
                if (col < FPD && row < nA)
                    g[(long long)sAtom[row] * FPD + col] = f2bf(acc7[rt][r]);
            }
    }
}

// ---------------- bucketing by COLUMN range (4096 cols/bucket) ----------------
// Rationale: device-scope atomicAdd goes out to the fabric (~20 G atomics/s,
// measured: 5M atomics = 248us with 156MB WRITE in both R8 and R9). Col-range
// bucketing lets the scatter accumulate in LDS and write each output once.
__global__ __launch_bounds__(256) void bucket_hist(const int* __restrict__ cols,
                                                   int* __restrict__ bcnt) {
    __shared__ int h[NBUCK];
    const int t = threadIdx.x;
    if (t < NBUCK) h[t] = 0;
    __syncthreads();
    const int nv = NNZ_C / 4;
    for (int vk = blockIdx.x * 256 + t; vk < nv; vk += gridDim.x * 256) {
        i32x4 c = __builtin_nontemporal_load((const i32x4*)cols + vk);
        atomicAdd(&h[c.x >> CBITS], 1);
        atomicAdd(&h[c.y >> CBITS], 1);
        atomicAdd(&h[c.z >> CBITS], 1);
        atomicAdd(&h[c.w >> CBITS], 1);
    }
    __syncthreads();
    if (t < NBUCK) atomicAdd(&bcnt[t], h[t]);
}

__global__ void bucket_scan(const int* __restrict__ bcnt, int* __restrict__ bbase,
                            int* __restrict__ bcur) {
    if (threadIdx.x == 0 && blockIdx.x == 0) {
        int s = 0;
        for (int i = 0; i < NBUCK; i++) { bbase[i] = s; bcur[i] = s; s += bcnt[i]; }
    }
}

__global__ __launch_bounds__(256) void bucket_scatter(
    const int* __restrict__ rows, const int* __restrict__ cols,
    const float* __restrict__ vals, int* __restrict__ bcur,
    int* __restrict__ brows, int* __restrict__ bcols, float* __restrict__ bvals) {
    __shared__ int lcnt[NBUCK];
    __shared__ int lcur[NBUCK];
    const int t = threadIdx.x;
    if (t < NBUCK) lcnt[t] = 0;
    __syncthreads();
    const int vk0 = blockIdx.x * 2048;  // 2048 vec4 = 8192 entries
    i32x4 ccache[8];
    int nb[8][4];
#pragma unroll
    for (int i = 0; i < 8; i++) {
        int vk = vk0 + i * 256 + t;
        if (vk * 4 < NNZ_C) {
            i32x4 c = __builtin_nontemporal_load((const i32x4*)cols + vk);
            ccache[i] = c;
            nb[i][0] = c.x >> CBITS; nb[i][1] = c.y >> CBITS;
            nb[i][2] = c.z >> CBITS; nb[i][3] = c.w >> CBITS;
            atomicAdd(&lcnt[nb[i][0]], 1);
            atomicAdd(&lcnt[nb[i][1]], 1);
            atomicAdd(&lcnt[nb[i][2]], 1);
            atomicAdd(&lcnt[nb[i][3]], 1);
        } else {
            nb[i][0] = -1;
        }
    }
    __syncthreads();
    if (t < NBUCK) lcur[t] = atomicAdd(&bcur[t], lcnt[t]);
    __syncthreads();
#pragma unroll
    for (int i = 0; i < 8; i++) {
        int vk = vk0 + i * 256 + t;
        if (vk * 4 < NNZ_C) {
            i32x4 r = __builtin_nontemporal_load((const i32x4*)rows + vk);
            f32x4 v = __builtin_nontemporal_load((const f32x4*)vals + vk);
            int rr[4] = {r.x, r.y, r.z, r.w};
            int cc[4] = {ccache[i].x, ccache[i].y, ccache[i].z, ccache[i].w};
            float vv[4] = {v.x, v.y, v.z, v.w};
#pragma unroll
            for (int u = 0; u < 4; u++) {
                int pos = atomicAdd(&lcur[nb[i][u]], 1);
                brows[pos] = rr[u];
                bcols[pos] = cc[u];
                bvals[pos] = vv[u];
            }
        }
    }
}

// scatter with LDS accumulation: block (b,s) accumulates bucket b's slice in
// 16KB LDS, then plain-stores (no global atomics) into forcesP slot s.
__global__ __launch_bounds__(256) void scatter_lds(
    const int* __restrict__ brows, const int* __restrict__ bcols,
    const float* __restrict__ bvals, const int* __restrict__ bbase,
    const int* __restrict__ bcnt, const ushort_t* __restrict__ g,
    float* __restrict__ forcesP) {
    __shared__ float facc[1 << CBITS];
    const int b = blockIdx.x >> 3;
    const int s = blockIdx.x & 7;
    const int t = threadIdx.x;
    for (int i = t; i < (1 << CBITS); i += 256) facc[i] = 0.f;
    __syncthreads();
    const int base = bbase[b];
    const int end = base + bcnt[b];
    for (int i = base + s * 256 + t; i < end; i += 8 * 256) {
        int r = brows[i];
        int c = bcols[i];
        float v = bvals[i];
        atomicAdd(&facc[c & ((1 << CBITS) - 1)], -v * bf2f(g[r]));
    }
    __syncthreads();
    const int colbase = b << CBITS;
    float* fp = forcesP + (size_t)s * NFORCE;
    for (int i = t; i < (1 << CBITS); i += 256) {
        int col = colbase + i;
        if (col < NFORCE) __builtin_nontemporal_store(facc[i], &fp[col]);
    }
}

// fallback direct scatter (used when ws too small for buckets)
__global__ __launch_bounds__(256) void scatter_forces(
    const int* __restrict__ rows, const int* __restrict__ cols,
    const float* __restrict__ vals, const ushort_t* __restrict__ g,
    float* __restrict__ forcesP) {
    int k = blockIdx.x * 256 + threadIdx.x;
    if (k >= NNZ_C / 4) return;
    int slot = blockIdx.x & 7;
    i32x4 r = __builtin_nontemporal_load((const i32x4*)rows + k);
    i32x4 c = __builtin_nontemporal_load((const i32x4*)cols + k);
    f32x4 v = __builtin_nontemporal_load((const f32x4*)vals + k);
    float* fp = forcesP + (size_t)slot * NFORCE;
    atomicAdd(&fp[c.x], -v.x * bf2f(g[r.x]));
    atomicAdd(&fp[c.y], -v.y * bf2f(g[r.y]));
    atomicAdd(&fp[c.z], -v.z * bf2f(g[r.z]));
    atomicAdd(&fp[c.w], -v.w * bf2f(g[r.w]));
}

__global__ void reduce_forces(const float* __restrict__ forcesP, float* __restrict__ forces) {
    int i = blockIdx.x * blockDim.x + threadIdx.x;
    if (i >= NFORCE) return;
    float s = 0.f;
#pragma unroll
    for (int x = 0; x < 8; x++) s += forcesP[x * NFORCE + i];
    forces[i] = s;
}

extern "C" void kernel_launch(void* const* d_in, const int* in_sizes, int n_in,
                              void* d_out, int out_size, void* d_ws, size_t ws_size,
                              hipStream_t stream) {
    const float* fps = (const float*)d_in[0];
    const int* z = (const int*)d_in[1];
    const int* img = (const int*)d_in[2];
    const float* W1 = (const float*)d_in[3];
    const float* b1 = (const float*)d_in[4];
    const float* W2 = (const float*)d_in[5];
    const float* b2 = (const float*)d_in[6];
    const float* W3 = (const float*)d_in[7];
    const float* b3 = (const float*)d_in[8];
    const int* rows = (const int*)d_in[9];
    const int* cols = (const int*)d_in[10];
    const float* vals = (const float*)d_in[11];

    float* out = (float*)d_out;
    float* energy = out;
    float* forces = out + BB;

    char* ws = (char*)d_ws;
    int* counts = (int*)ws;                           // 256 B
    int* lists = (int*)(ws + 256);                    // 720000 B
    ushort_t* W1p = (ushort_t*)(ws + 720384);         // 393216 B
    ushort_t* W2p = (ushort_t*)(ws + 1113600);        // 1572864 B
    ushort_t* W2Tp = (ushort_t*)(ws + 2686464);       // 1572864 B
    ushort_t* W1Tp = (ushort_t*)(ws + 4259328);       // 393216 B
    ushort_t* g = (ushort_t*)(ws + 4652544);          // 14400000 B
    float* forcesP = (float*)(ws + 19052544);         // 5760000 B
    int* bmeta = (int*)(ws + 24812544);               // bcnt[64],bbase[64],bcur[64]
    int* bcnt = bmeta, *bbase = bmeta + 64, *bcur = bmeta + 128;
    int* brows = (int*)(ws + 24813568);               // 20 MB
    int* bcols = (int*)(ws + 44813568);               // 20 MB
    float* bvals = (float*)(ws + 64813568);           // 20 MB -> 84813568 total
    const size_t WS_NEED = 84813568;
    (void)in_sizes; (void)n_in; (void)out_size;

    (void)hipMemsetAsync(d_out, 0, (size_t)(BB + NFORCE) * sizeof(float), stream);
    (void)hipMemsetAsync(counts, 0, 256, stream);

    build_lists<<<(N_ATOMS + 255) / 256, 256, 0, stream>>>(z, counts, lists);
    pack_W2<<<(EE * 16 * 32 * 512 + 255) / 256, 256, 0, stream>>>(W2, W2p, W2Tp);
    pack_W1<<<(EE * 4 * 32 * 512 + 255) / 256, 256, 0, stream>>>(W1, W1p);
    pack_W1T<<<(EE * 16 * 8 * 512 + 255) / 256, 256, 0, stream>>>(W1, W1Tp);

    int tiles = (N_ATOMS + TB - 1) / TB;
    mlp_mfma<<<EE * tiles, 512, 0, stream>>>(fps, img, b1, b2, W3, b3,
                                             W1p, W2p, W2Tp, W1Tp,
                                             counts, lists, energy, g);

    if (ws_size >= WS_NEED) {
        (void)hipMemsetAsync(bmeta, 0, 768, stream);
        bucket_hist<<<256, 256, 0, stream>>>(cols, bcnt);
        bucket_scan<<<1, 64, 0, stream>>>(bcnt, bbase, bcur);
        bucket_scatter<<<(NNZ_C + 8191) / 8192, 256, 0, stream>>>(
            rows, cols, vals, bcur, brows, bcols, bvals);
        scatter_lds<<<NBUCK * 8, 256, 0, stream>>>(brows, bcols, bvals, bbase,
                                                   bcnt, g, forcesP);
    } else {
        (void)hipMemsetAsync(forcesP, 0, (size_t)8 * NFORCE * sizeof(float), stream);
        scatter_forces<<<(NNZ_C / 4 + 255) / 256, 256, 0, stream>>>(rows, cols, vals, g, forcesP);
    }
    reduce_forces<<<(NFORCE + 255) / 256, 256, 0, stream>>>(forcesP, forces);
}

// Round 11
// 455.279 us; speedup vs baseline: 1.3998x; 1.0862x over previous
//
#include <hip/hip_runtime.h>

#define N_ATOMS 60000
#define FPD 120
#define HD 512
#define EE 3
#define BB 600
#define NNZ_C 5000000
#define NFORCE (3 * N_ATOMS)
#define TB 32
#define CBITS 12                       // 4096 cols per bucket (16KB f32 LDS)
#define NBUCK ((NFORCE + 4095) / 4096) // 44
#define NSLOT 16

typedef unsigned short ushort_t;
typedef unsigned int uint_t;
typedef unsigned long long u64_t;
typedef __attribute__((ext_vector_type(8))) __bf16 bf16x8;
typedef __attribute__((ext_vector_type(4))) float f32x4;
typedef __attribute__((ext_vector_type(4))) int i32x4;

union BF8 { f32x4 f; bf16x8 h; };

__device__ __forceinline__ ushort_t f2bf(float x) {
    uint_t u = __builtin_bit_cast(uint_t, x);
    u = (u + 0x7FFFu + ((u >> 16) & 1u)) >> 16;
    return (ushort_t)u;
}
__device__ __forceinline__ float bf2f(ushort_t s) {
    uint_t u = ((uint_t)s) << 16;
    return __builtin_bit_cast(float, u);
}
__device__ __forceinline__ float fast_tanh(float x) {
    float e2 = __expf(2.f * x);
    return fmaf(-2.f, __frcp_rn(e2 + 1.f), 1.f);
}

// ---------------- build per-element atom lists (block-aggregated atomics) -----
__global__ __launch_bounds__(256) void build_lists(const int* __restrict__ z,
                                                   int* __restrict__ counts,
                                                   int* __restrict__ lists) {
    __shared__ int lc[3];
    __shared__ int lbase[3];
    const int t = threadIdx.x;
    if (t < 3) lc[t] = 0;
    __syncthreads();
    const int i = blockIdx.x * 256 + t;
    int e = 0, pos = 0;
    if (i < N_ATOMS) {
        int zi = z[i];
        e = (zi == 1) ? 0 : ((zi == 8) ? 1 : 2);
        pos = atomicAdd(&lc[e], 1);
    }
    __syncthreads();
    if (t < 3) lbase[t] = atomicAdd(&counts[t], lc[t]);
    __syncthreads();
    if (i < N_ATOMS) lists[e * N_ATOMS + lbase[e] + pos] = i;
}

// ---------------- pack all weights (fused) into MFMA B-fragment order --------
// Lane L of B-frag holds B[k = ks*32 + (L>>4)*8 + j][n = ct*16 + (L&15)], j=0..7.
#define R_W2 (EE * 16 * 32 * 512)
#define R_W1 (EE * 4 * 32 * 512)
#define R_W1T (EE * 16 * 8 * 512)
__global__ __launch_bounds__(256) void pack_all(
    const float* __restrict__ W1, const float* __restrict__ W2,
    ushort_t* __restrict__ W1p, ushort_t* __restrict__ W2p,
    ushort_t* __restrict__ W2Tp, ushort_t* __restrict__ W1Tp) {
    int idx = blockIdx.x * 256 + threadIdx.x;
    if (idx < R_W2) {
        int p = idx;
        int j = p & 7, L = (p >> 3) & 63, ct = (p >> 9) & 31, ks = (p >> 14) & 15, e = p >> 18;
        int k = ks * 32 + ((L >> 4) << 3) + j;
        int n = (ct << 4) + (L & 15);
        W2p[p]  = f2bf(W2[((e << 9) + k) * 512 + n]);
        W2Tp[p] = f2bf(W2[((e << 9) + n) * 512 + k]);
    } else if (idx < R_W2 + R_W1) {
        int p = idx - R_W2;
        int j = p & 7, L = (p >> 3) & 63, ct = (p >> 9) & 31, ks = (p >> 14) & 3, e = p >> 16;
        int k = ks * 32 + ((L >> 4) << 3) + j;
        int n = (ct << 4) + (L & 15);
        W1p[p] = (k < FPD) ? f2bf(W1[(e * FPD + k) * 512 + n]) : (ushort_t)0;
    } else if (idx < R_W2 + R_W1 + R_W1T) {
        int p = idx - R_W2 - R_W1;
        int j = p & 7, L = (p >> 3) & 63, ct = (p >> 9) & 7, ks = (p >> 12) & 15, e = p >> 16;
        int k = ks * 32 + ((L >> 4) << 3) + j;
        int n = (ct << 4) + (L & 15);
        W1Tp[p] = (n < FPD) ? f2bf(W1[(e * FPD + n) * 512 + k]) : (ushort_t)0;
    }
}

#define STR 520
#define FSTR 136

// ---------------- fused fwd+bwd MLP, 32 atoms/block, 8 waves, MFMA ------------
// K-loops batch-load 4 iterations of B-fragments (16 frags = 64 VGPR) before
// the MFMA burst: 4x in-flight bytes per wave (latency*BW needs ~9KB/CU in
// flight; the 1-iter version had ~1KB -> MLP-starved at 202us).
__global__ __launch_bounds__(512, 4) void mlp_mfma(
    const float* __restrict__ fps, const int* __restrict__ image_idx,
    const float* __restrict__ b1, const float* __restrict__ b2,
    const float* __restrict__ W3, const float* __restrict__ b3,
    const ushort_t* __restrict__ W1p, const ushort_t* __restrict__ W2p,
    const ushort_t* __restrict__ W2Tp, const ushort_t* __restrict__ W1Tp,
    const int* __restrict__ counts, const int* __restrict__ lists,
    float* __restrict__ energy, ushort_t* __restrict__ g) {
    __shared__ ushort_t sH1[TB * STR];
    __shared__ ushort_t sD[TB * STR];
    __shared__ float sW3[512];
    __shared__ float eAcc[TB];
    __shared__ int sAtom[TB];
    __shared__ int sImg[TB];

    const int e = blockIdx.x % EE;
    const int tile = blockIdx.x / EE;
    const int cnt = counts[e];
    const int base = tile * TB;
    if (base >= cnt) return;
    const int nA = min(TB, cnt - base);
    const int* lst = lists + e * N_ATOMS + base;

    const int t = threadIdx.x;
    const int w = t >> 6, lane = t & 63, quad = lane >> 4, lc = lane & 15;

    if (t < TB) {
        int a = (t < nA) ? lst[t] : -1;
        sAtom[t] = a;
        sImg[t] = (a >= 0) ? image_idx[a] : 0;
        eAcc[t] = 0.f;
    }
    if (t < 512) sW3[t] = W3[e * 512 + t];
    for (int i = t; i < TB * 128; i += 512) {
        int a = i >> 7, f = i & 127;
        float v = 0.f;
        if (f < FPD && a < nA) v = __builtin_nontemporal_load(&fps[(long long)lst[a] * FPD + f]);
        sD[a * FSTR + f] = f2bf(v);
    }
    __syncthreads();

    float b1c[4], b2c[4];
#pragma unroll
    for (int c = 0; c < 4; c++) {
        int col = w * 64 + c * 16 + lc;
        b1c[c] = b1[e * 512 + col];
        b2c[c] = b2[e * 512 + col];
    }

    f32x4 acc[2][4];

    // ---- stage 1: h1 = tanh(fp @ W1 + b1); all 16 frags batched ----
#pragma unroll
    for (int rt = 0; rt < 2; rt++)
#pragma unroll
        for (int c = 0; c < 4; c++) acc[rt][c] = (f32x4)0.f;
    {
        const ushort_t* wbase = W1p + ((size_t)(e * 4) * 32 + w * 4) * 512 + lane * 8;
        BF8 bb[4][4];
#pragma unroll
        for (int ks = 0; ks < 4; ks++)
#pragma unroll
            for (int c = 0; c < 4; c++)
                bb[ks][c].f = *(const f32x4*)(wbase + ((size_t)ks * 32 + c) * 512);
#pragma unroll
        for (int ks = 0; ks < 4; ks++) {
            bf16x8 a0 = *(const bf16x8*)((const char*)sD + lc * (FSTR * 2) + ks * 64 + quad * 16);
            bf16x8 a1 = *(const bf16x8*)((const char*)sD + (16 + lc) * (FSTR * 2) + ks * 64 + quad * 16);
#pragma unroll
            for (int c = 0; c < 4; c++) {
                acc[0][c] = __builtin_amdgcn_mfma_f32_16x16x32_bf16(a0, bb[ks][c].h, acc[0][c], 0, 0, 0);
                acc[1][c] = __builtin_amdgcn_mfma_f32_16x16x32_bf16(a1, bb[ks][c].h, acc[1][c], 0, 0, 0);
            }
        }
    }
#pragma unroll
    for (int c = 0; c < 4; c++) {
        int col = w * 64 + c * 16 + lc;
#pragma unroll
        for (int rt = 0; rt < 2; rt++)
#pragma unroll
            for (int r = 0; r < 4; r++) {
                int row = rt * 16 + quad * 4 + r;
                sH1[row * STR + col] = f2bf(fast_tanh(acc[rt][c][r] + b1c[c]));
            }
    }
    __syncthreads();

    // ---- stage 2: h2 = tanh(h1 @ W2 + b2); dh2; energy (chunks of 4 ks) ----
#pragma unroll
    for (int rt = 0; rt < 2; rt++)
#pragma unroll
        for (int c = 0; c < 4; c++) acc[rt][c] = (f32x4)0.f;
    {
        const ushort_t* wbase = W2p + ((size_t)(e * 16) * 32 + w * 4) * 512 + lane * 8;
#pragma unroll
        for (int ksc = 0; ksc < 4; ksc++) {
            BF8 bb[4][4];
#pragma unroll
            for (int kk = 0; kk < 4; kk++)
#pragma unroll
                for (int c = 0; c < 4; c++)
                    bb[kk][c].f = *(const f32x4*)(wbase + (size_t)(ksc * 4 + kk) * 32 * 512 + (size_t)c * 512);
#pragma unroll
            for (int kk = 0; kk < 4; kk++) {
                int ks = ksc * 4 + kk;
                bf16x8 a0 = *(const bf16x8*)((const char*)sH1 + lc * (STR * 2) + ks * 64 + quad * 16);
                bf16x8 a1 = *(const bf16x8*)((const char*)sH1 + (16 + lc) * (STR * 2) + ks * 64 + quad * 16);
#pragma unroll
                for (int c = 0; c < 4; c++) {
                    acc[0][c] = __builtin_amdgcn_mfma_f32_16x16x32_bf16(a0, bb[kk][c].h, acc[0][c], 0, 0, 0);
                    acc[1][c] = __builtin_amdgcn_mfma_f32_16x16x32_bf16(a1, bb[kk][c].h, acc[1][c], 0, 0, 0);
                }
            }
        }
    }
    {
        float ep[2][4];
#pragma unroll
        for (int rt = 0; rt < 2; rt++)
#pragma unroll
            for (int r = 0; r < 4; r++) ep[rt][r] = 0.f;
#pragma unroll
        for (int c = 0; c < 4; c++) {
            int col = w * 64 + c * 16 + lc;
            float w3c = sW3[col];
#pragma unroll
            for (int rt = 0; rt < 2; rt++)
#pragma unroll
                for (int r = 0; r < 4; r++) {
                    int row = rt * 16 + quad * 4 + r;
                    float h2 = fast_tanh(acc[rt][c][r] + b2c[c]);
                    ep[rt][r] += h2 * w3c;
                    sD[row * STR + col] = f2bf(w3c * (1.f - h2 * h2));
                }
        }
#pragma unroll
        for (int rt = 0; rt < 2; rt++)
#pragma unroll
            for (int r = 0; r < 4; r++) {
                float p = ep[rt][r];
                p += __shfl_xor(p, 1);
                p += __shfl_xor(p, 2);
                p += __shfl_xor(p, 4);
                p += __shfl_xor(p, 8);
                if (lc == 0) atomicAdd(&eAcc[rt * 16 + quad * 4 + r], p);
            }
    }
    __syncthreads();

    if (t < nA) atomicAdd(&energy[sImg[t]], eAcc[t] + b3[e]);

    // ---- stage 5: dh1 = (dh2 @ W2^T) * (1-h1^2) (chunks of 4 ks) ----
#pragma unroll
    for (int rt = 0; rt < 2; rt++)
#pragma unroll
        for (int c = 0; c < 4; c++) acc[rt][c] = (f32x4)0.f;
    {
        const ushort_t* wbase = W2Tp + ((size_t)(e * 16) * 32 + w * 4) * 512 + lane * 8;
#pragma unroll
        for (int ksc = 0; ksc < 4; ksc++) {
            BF8 bb[4][4];
#pragma unroll
            for (int kk = 0; kk < 4; kk++)
#pragma unroll
                for (int c = 0; c < 4; c++)
                    bb[kk][c].f = *(const f32x4*)(wbase + (size_t)(ksc * 4 + kk) * 32 * 512 + (size_t)c * 512);
#pragma unroll
            for (int kk = 0; kk < 4; kk++) {
                int ks = ksc * 4 + kk;
                bf16x8 a0 = *(const bf16x8*)((const char*)sD + lc * (STR * 2) + ks * 64 + quad * 16);
                bf16x8 a1 = *(const bf16x8*)((const char*)sD + (16 + lc) * (STR * 2) + ks * 64 + quad * 16);
#pragma unroll
                for (int c = 0; c < 4; c++) {
                    acc[0][c] = __builtin_amdgcn_mfma_f32_16x16x32_bf16(a0, bb[kk][c].h, acc[0][c], 0, 0, 0);
                    acc[1][c] = __builtin_amdgcn_mfma_f32_16x16x32_bf16(a1, bb[kk][c].h, acc[1][c], 0, 0, 0);
                }
            }
        }
    }
#pragma unroll
    for (int c = 0; c < 4; c++) {
        int col = w * 64 + c * 16 + lc;
#pragma unroll
        for (int rt = 0; rt < 2; rt++)
#pragma unroll
            for (int r = 0; r < 4; r++) {
                int row = rt * 16 + quad * 4 + r;
                float h1v = bf2f(sH1[row * STR + col]);
                acc[rt][c][r] *= (1.f - h1v * h1v);
            }
    }
    __syncthreads();
#pragma unroll
    for (int c = 0; c < 4; c++) {
        int col = w * 64 + c * 16 + lc;
#pragma unroll
        for (int rt = 0; rt < 2; rt++)
#pragma unroll
            for (int r = 0; r < 4; r++) {
                int row = rt * 16 + quad * 4 + r;
                sH1[row * STR + col] = f2bf(acc[rt][c][r]);
            }
    }
    __syncthreads();

    // ---- stage 7: g = dh1 @ W1^T (2 chunks of 8 frags) ----
    f32x4 acc7[2];
#pragma unroll
    for (int rt = 0; rt < 2; rt++) acc7[rt] = (f32x4)0.f;
    {
        const ushort_t* wbase = W1Tp + ((size_t)(e * 16) * 8 + w) * 512 + lane * 8;
#pragma unroll
        for (int ksc = 0; ksc < 2; ksc++) {
            BF8 bb[8];
#pragma unroll
            for (int kk = 0; kk < 8; kk++)
                bb[kk].f = *(const f32x4*)(wbase + (size_t)(ksc * 8 + kk) * 8 * 512);
#pragma unroll
            for (int kk = 0; kk < 8; kk++) {
                int ks = ksc * 8 + kk;
                bf16x8 a0 = *(const bf16x8*)((const char*)sH1 + lc * (STR * 2) + ks * 64 + quad * 16);
                bf16x8 a1 = *(const bf16x8*)((const char*)sH1 + (16 + lc) * (STR * 2) + ks * 64 + quad * 16);
                acc7[0] = __builtin_amdgcn_mfma_f32_16x16x32_bf16(a0, bb[kk].h, acc7[0], 0, 0, 0);
                acc7[1] = __builtin_amdgcn_mfma_f32_16x16x32_bf16(a1, bb[kk].h, acc7[1], 0, 0, 0);
            }
        }
    }
    {
        int col = w * 16 + lc;
#pragma unroll
        for (int rt = 0; rt < 2; rt++)
#pragma unroll
            for (int r = 0; r < 4; r++) {
                int row = rt * 16 + quad * 4 + r;
                if (col < FPD && row < nA)
                    g[(long long)sAtom[row] * FPD + col] = f2bf(acc7[rt][r]);
            }
    }
}

// ---------------- bucketing by COLUMN range (4096 cols/bucket) ----------------
// Entries packed into 8B: row(23b) | col_in_bucket(12b) | val(bf16,16b).
__global__ __launch_bounds__(256) void bucket_hist(const int* __restrict__ cols,
                                                   int* __restrict__ bcnt) {
    __shared__ int h[NBUCK];
    const int t = threadIdx.x;
    if (t < NBUCK) h[t] = 0;
    __syncthreads();
    const int nv = NNZ_C / 4;
    for (int vk = blockIdx.x * 256 + t; vk < nv; vk += gridDim.x * 256) {
        i32x4 c = __builtin_nontemporal_load((const i32x4*)cols + vk);
        atomicAdd(&h[c.x >> CBITS], 1);
        atomicAdd(&h[c.y >> CBITS], 1);
        atomicAdd(&h[c.z >> CBITS], 1);
        atomicAdd(&h[c.w >> CBITS], 1);
    }
    __syncthreads();
    if (t < NBUCK) atomicAdd(&bcnt[t], h[t]);
}

__global__ void bucket_scan(const int* __restrict__ bcnt, int* __restrict__ bbase,
                            int* __restrict__ bcur) {
    if (threadIdx.x == 0 && blockIdx.x == 0) {
        int s = 0;
        for (int i = 0; i < NBUCK; i++) { bbase[i] = s; bcur[i] = s; s += bcnt[i]; }
    }
}

__global__ __launch_bounds__(256) void bucket_scatter(
    const int* __restrict__ rows, const int* __restrict__ cols,
    const float* __restrict__ vals, int* __restrict__ bcur,
    u64_t* __restrict__ bpack) {
    __shared__ int lcnt[NBUCK];
    __shared__ int lcur[NBUCK];
    const int t = threadIdx.x;
    if (t < NBUCK) lcnt[t] = 0;
    __syncthreads();
    const int vk0 = blockIdx.x * 2048;  // 2048 vec4 = 8192 entries
    i32x4 ccache[8];
    int nb[8][4];
#pragma unroll
    for (int i = 0; i < 8; i++) {
        int vk = vk0 + i * 256 + t;
        if (vk * 4 < NNZ_C) {
            i32x4 c = __builtin_nontemporal_load((const i32x4*)cols + vk);
            ccache[i] = c;
            nb[i][0] = c.x >> CBITS; nb[i][1] = c.y >> CBITS;
            nb[i][2] = c.z >> CBITS; nb[i][3] = c.w >> CBITS;
            atomicAdd(&lcnt[nb[i][0]], 1);
            atomicAdd(&lcnt[nb[i][1]], 1);
            atomicAdd(&lcnt[nb[i][2]], 1);
            atomicAdd(&lcnt[nb[i][3]], 1);
        } else {
            nb[i][0] = -1;
        }
    }
    __syncthreads();
    if (t < NBUCK) lcur[t] = atomicAdd(&bcur[t], lcnt[t]);
    __syncthreads();
#pragma unroll
    for (int i = 0; i < 8; i++) {
        int vk = vk0 + i * 256 + t;
        if (vk * 4 < NNZ_C) {
            i32x4 r = __builtin_nontemporal_load((const i32x4*)rows + vk);
            f32x4 v = __builtin_nontemporal_load((const f32x4*)vals + vk);
            int rr[4] = {r.x, r.y, r.z, r.w};
            int cc[4] = {ccache[i].x, ccache[i].y, ccache[i].z, ccache[i].w};
            float vv[4] = {v.x, v.y, v.z, v.w};
#pragma unroll
            for (int u = 0; u < 4; u++) {
                int pos = atomicAdd(&lcur[nb[i][u]], 1);
                u64_t pk = (u64_t)(uint_t)rr[u] |
                           ((u64_t)(uint_t)(cc[u] & ((1 << CBITS) - 1)) << 23) |
                           ((u64_t)f2bf(vv[u]) << 35);
                bpack[pos] = pk;
            }
        }
    }
}

// scatter with LDS accumulation: block (b,s) accumulates bucket b's slice in
// 16KB LDS, then plain-stores (no global atomics) into forcesP slot s.
__global__ __launch_bounds__(256) void scatter_lds(
    const u64_t* __restrict__ bpack, const int* __restrict__ bbase,
    const int* __restrict__ bcnt, const ushort_t* __restrict__ g,
    float* __restrict__ forcesP) {
    __shared__ float facc[1 << CBITS];
    const int b = blockIdx.x >> 4;
    const int s = blockIdx.x & (NSLOT - 1);
    const int t = threadIdx.x;
    for (int i = t; i < (1 << CBITS); i += 256) facc[i] = 0.f;
    __syncthreads();
    const int base = bbase[b];
    const int end = base + bcnt[b];
    for (int i = base + s * 256 + t; i < end; i += NSLOT * 256) {
        u64_t pk = bpack[i];
        int r = (int)(pk & 0x7FFFFFu);
        int cin = (int)((pk >> 23) & 0xFFFu);
        float v = bf2f((ushort_t)(pk >> 35));
        atomicAdd(&facc[cin], -v * bf2f(g[r]));
    }
    __syncthreads();
    const int colbase = b << CBITS;
    float* fp = forcesP + (size_t)s * NFORCE;
    for (int i = t; i < (1 << CBITS); i += 256) {
        int col = colbase + i;
        if (col < NFORCE) __builtin_nontemporal_store(facc[i], &fp[col]);
    }
}

__global__ void reduce_forces(const float* __restrict__ forcesP, float* __restrict__ forces) {
    int i = blockIdx.x * blockDim.x + threadIdx.x;
    if (i >= NFORCE) return;
    float s = 0.f;
#pragma unroll
    for (int x = 0; x < NSLOT; x++) s += forcesP[(size_t)x * NFORCE + i];
    forces[i] = s;
}

// fallback direct scatter (used when ws too small for buckets)
__global__ __launch_bounds__(256) void scatter_forces(
    const int* __restrict__ rows, const int* __restrict__ cols,
    const float* __restrict__ vals, const ushort_t* __restrict__ g,
    float* __restrict__ forcesP) {
    int k = blockIdx.x * 256 + threadIdx.x;
    if (k >= NNZ_C / 4) return;
    int slot = blockIdx.x & (NSLOT - 1);
    i32x4 r = __builtin_nontemporal_load((const i32x4*)rows + k);
    i32x4 c = __builtin_nontemporal_load((const i32x4*)cols + k);
    f32x4 v = __builtin_nontemporal_load((const f32x4*)vals + k);
    float* fp = forcesP + (size_t)slot * NFORCE;
    atomicAdd(&fp[c.x], -v.x * bf2f(g[r.x]));
    atomicAdd(&fp[c.y], -v.y * bf2f(g[r.y]));
    atomicAdd(&fp[c.z], -v.z * bf2f(g[r.z]));
    atomicAdd(&fp[c.w], -v.w * bf2f(g[r.w]));
}

extern "C" void kernel_launch(void* const* d_in, const int* in_sizes, int n_in,
                              void* d_out, int out_size, void* d_ws, size_t ws_size,
                              hipStream_t stream) {
    const float* fps = (const float*)d_in[0];
    const int* z = (const int*)d_in[1];
    const int* img = (const int*)d_in[2];
    const float* W1 = (const float*)d_in[3];
    const float* b1 = (const float*)d_in[4];
    const float* W2 = (const float*)d_in[5];
    const float* b2 = (const float*)d_in[6];
    const float* W3 = (const float*)d_in[7];
    const float* b3 = (const float*)d_in[8];
    const int* rows = (const int*)d_in[9];
    const int* cols = (const int*)d_in[10];
    const float* vals = (const float*)d_in[11];

    float* out = (float*)d_out;
    float* energy = out;
    float* forces = out + BB;

    char* ws = (char*)d_ws;
    int* counts = (int*)ws;                           // 256 B
    int* lists = (int*)(ws + 256);                    // 720000 B
    ushort_t* W1p = (ushort_t*)(ws + 720384);         // 393216 B
    ushort_t* W2p = (ushort_t*)(ws + 1113600);        // 1572864 B
    ushort_t* W2Tp = (ushort_t*)(ws + 2686464);       // 1572864 B
    ushort_t* W1Tp = (ushort_t*)(ws + 4259328);       // 393216 B
    ushort_t* g = (ushort_t*)(ws + 4652544);          // 14400000 B
    float* forcesP = (float*)(ws + 19052544);         // 16*720000 = 11520000 B
    int* bmeta = (int*)(ws + 30572544);               // bcnt[64],bbase[64],bcur[64]
    int* bcnt = bmeta, *bbase = bmeta + 64, *bcur = bmeta + 128;
    u64_t* bpack = (u64_t*)(ws + 30573568);           // 40 MB -> 70573568 total
    const size_t WS_NEED = 70573568;
    (void)in_sizes; (void)n_in; (void)out_size;

    (void)hipMemsetAsync(energy, 0, BB * sizeof(float), stream);  // forces fully overwritten
    (void)hipMemsetAsync(counts, 0, 256, stream);

    build_lists<<<(N_ATOMS + 255) / 256, 256, 0, stream>>>(z, counts, lists);
    pack_all<<<(R_W2 + R_W1 + R_W1T + 255) / 256, 256, 0, stream>>>(
        W1, W2, W1p, W2p, W2Tp, W1Tp);

    int tiles = (N_ATOMS + TB - 1) / TB;
    mlp_mfma<<<EE * tiles, 512, 0, stream>>>(fps, img, b1, b2, W3, b3,
                                             W1p, W2p, W2Tp, W1Tp,
                                             counts, lists, energy, g);

    if (ws_size >= WS_NEED) {
        (void)hipMemsetAsync(bmeta, 0, 768, stream);
        bucket_hist<<<256, 256, 0, stream>>>(cols, bcnt);
        bucket_scan<<<1, 64, 0, stream>>>(bcnt, bbase, bcur);
        bucket_scatter<<<(NNZ_C + 8191) / 8192, 256, 0, stream>>>(
            rows, cols, vals, bcur, bpack);
        scatter_lds<<<NBUCK * NSLOT, 256, 0, stream>>>(bpack, bbase, bcnt, g, forcesP);
        reduce_forces<<<(NFORCE + 255) / 256, 256, 0, stream>>>(forcesP, forces);
    } else {
        (void)hipMemsetAsync(forcesP, 0, (size_t)NSLOT * NFORCE * sizeof(float), stream);
        scatter_forces<<<(NNZ_C / 4 + 255) / 256, 256, 0, stream>>>(rows, cols, vals, g, forcesP);
        reduce_forces<<<(NFORCE + 255) / 256, 256, 0, stream>>>(forcesP, forces);
    }
}